// Round 5
// baseline (1412.702 us; speedup 1.0000x reference)
//
#include <hip/hip_runtime.h>
#include <math.h>

#define N_ROWS 12544   // 16*28*28
#define C_DIM  1536
#define M_ROWS 16384
#define BATCH  16

typedef long  i64;
typedef float f32x4 __attribute__((ext_vector_type(4)));
typedef unsigned char u8;

// order-preserving float->uint key for atomicMin
__device__ __forceinline__ unsigned fkey(float f) {
  unsigned u = __float_as_uint(f);
  return (u & 0x80000000u) ? ~u : (u | 0x80000000u);
}
__device__ __forceinline__ float funkey(unsigned k) {
  unsigned u = (k & 0x80000000u) ? (k ^ 0x80000000u) : ~k;
  return __uint_as_float(u);
}

__device__ __forceinline__ void gl_lds16(const void* g, void* l) {
  __builtin_amdgcn_global_load_lds(
      (__attribute__((address_space(1))) void*)(g),
      (__attribute__((address_space(3))) void*)(l), 16, 0, 0);
}

// ---------------- Kernel A: build fp8 e4m3 feature rows + x_sq -------------
__global__ void prep_feats(const float* __restrict__ feat2,
                           const float* __restrict__ feat3,
                           u8* __restrict__ feats,
                           float* __restrict__ xsq) {
  const int n = blockIdx.x;
  const int t = threadIdx.x;
  const int b = n / 784;
  const int rem = n % 784;
  const int y = rem / 28, x = rem % 28;
  const float sy = 0.5f * y - 0.25f;
  const float sx = 0.5f * x - 0.25f;
  const int y0 = (int)floorf(sy); const float fy = sy - (float)y0;
  const int x0 = (int)floorf(sx); const float fx = sx - (float)x0;
  const int y0c = max(y0, 0), y1c = min(y0 + 1, 13);
  const int x0c = max(x0, 0), x1c = min(x0 + 1, 13);
  const float w00 = (1.f-fy)*(1.f-fx), w01 = (1.f-fy)*fx;
  const float w10 = fy*(1.f-fx),       w11 = fy*fx;

  float ssq = 0.f;
  u8* orow = feats + (size_t)n * C_DIM;
  for (int c = t; c < C_DIM; c += 256) {
    float v;
    if (c < 512) {
      v = feat2[(((size_t)b * 512 + c) * 28 + y) * 28 + x];
    } else {
      const float* f3 = feat3 + ((size_t)b * 1024 + (c - 512)) * 196;
      v = w00 * f3[y0c*14 + x0c] + w01 * f3[y0c*14 + x1c]
        + w10 * f3[y1c*14 + x0c] + w11 * f3[y1c*14 + x1c];
    }
    int p = __builtin_amdgcn_cvt_pk_fp8_f32(v, 0.f, 0, false);  // e4m3 on gfx950
    orow[c] = (u8)(p & 0xFF);
    float vb = __builtin_amdgcn_cvt_f32_fp8(p, 0);
    ssq += vb * vb;
  }
  __shared__ float sred[4];
  for (int off = 32; off > 0; off >>= 1) ssq += __shfl_down(ssq, off, 64);
  if ((t & 63) == 0) sred[t >> 6] = ssq;
  __syncthreads();
  if (t == 0) xsq[n] = sred[0] + sred[1] + sred[2] + sred[3];
}

// ---------------- Kernel B: fp8 memory bank + m_sq ----------------
__global__ __launch_bounds__(384) void prep_mb(
    const float* __restrict__ mb, u8* __restrict__ mbb,
    float* __restrict__ msq) {
  const int j = blockIdx.x, t = threadIdx.x;   // 384 threads * 4 floats = 1536
  const float4 v = *(const float4*)(mb + (size_t)j * C_DIM + t * 4);
  int w = __builtin_amdgcn_cvt_pk_fp8_f32(v.x, v.y, 0, false);
  w = __builtin_amdgcn_cvt_pk_fp8_f32(v.z, v.w, w, true);      // bytes 2,3
  *(unsigned*)(mbb + (size_t)j * C_DIM + t * 4) = (unsigned)w;
  float q0 = __builtin_amdgcn_cvt_f32_fp8(w, 0);
  float q1 = __builtin_amdgcn_cvt_f32_fp8(w, 1);
  float q2 = __builtin_amdgcn_cvt_f32_fp8(w, 2);
  float q3 = __builtin_amdgcn_cvt_f32_fp8(w, 3);
  float ssq = q0*q0 + q1*q1 + q2*q2 + q3*q3;
  __shared__ float sred[6];
  for (int off = 32; off > 0; off >>= 1) ssq += __shfl_down(ssq, off, 64);
  if ((t & 63) == 0) sred[t >> 6] = ssq;
  __syncthreads();
  if (t == 0) {
    float s = 0.f;
#pragma unroll
    for (int w2 = 0; w2 < 6; w2++) s += sred[w2];
    msq[j] = s;
  }
}

// ---------------- init min buffer + score slots ----------------
__global__ void init_min(unsigned* __restrict__ dmin,
                         unsigned* __restrict__ score) {
  int i = blockIdx.x * 256 + threadIdx.x;
  if (i < N_ROWS) dmin[i] = 0xFFFFFFFFu;
  if (i < BATCH) score[i] = 0u;   // 0.0f; anomaly values are >= 0
}

// ---------------- Kernel C: fp8 MFMA GEMM + fused min over M ----------------
// 128x128 tile, BK=64 fp8 bytes. Same 16KB LDS and 4 gl_lds16/iter as the
// bf16 version but 24 iterations (half the barriers) and 32 MFMA/iter.
// mfma_f32_16x16x32_fp8_fp8: A/B frag = 8 consecutive k fp8 per lane
// (row=l16, k=quad*8), same geometry as bf16 16x16x32. C/D layout unchanged.
__global__ void gemm_min(const u8* __restrict__ X, const u8* __restrict__ Mb,
                         const float* __restrict__ msq,
                         unsigned* __restrict__ dmin) {
  __shared__ u8 As[128 * 64];
  __shared__ u8 Bs[128 * 64];
  __shared__ unsigned smin[128];
  const int t = threadIdx.x;
  const int mtile = blockIdx.x;   // 0..127 over M
  const int ntile = blockIdx.y;   // 0..97  over N
  const int lane = t & 63, wave = t >> 6;
  const int wm = wave >> 1, wn = wave & 1;
  if (t < 128) smin[t] = 0xFFFFFFFFu;

  const int row0 = ntile * 128;
  const int col0 = mtile * 128;
  // staging: thread t -> row t>>2, 16B chunk (t&3) of that row's 64B k-slab
  const int s_row = t >> 2;
  const int s_off = (t & 3) * 16;
  const u8* ga = X  + (size_t)(row0 + s_row) * C_DIM + s_off;
  const u8* gb = Mb + (size_t)(col0 + s_row) * C_DIM + s_off;
  u8* la = As + t * 16;
  u8* lb = Bs + t * 16;

  f32x4 acc[4][4];
  const f32x4 zero = {0.f, 0.f, 0.f, 0.f};
#pragma unroll
  for (int mi = 0; mi < 4; mi++)
#pragma unroll
    for (int ni = 0; ni < 4; ni++) acc[mi][ni] = zero;

  const int quad = lane >> 4, l16 = lane & 15;
  const u8* arow = As + (wm * 64 + l16) * 64 + quad * 8;
  const u8* brow = Bs + (wn * 64 + l16) * 64 + quad * 8;

  for (int k0 = 0; k0 < C_DIM; k0 += 64) {
    __syncthreads();
    gl_lds16(ga + k0,               la);
    gl_lds16(ga + 64 * C_DIM + k0,  la + 4096);   // rows 64..127
    gl_lds16(gb + k0,               lb);
    gl_lds16(gb + 64 * C_DIM + k0,  lb + 4096);
    __syncthreads();
    i64 af[4][2], bf[4][2];
#pragma unroll
    for (int mi = 0; mi < 4; mi++) {
      af[mi][0] = *(const i64*)(arow + mi * 1024);        // +16 rows = 1024B
      af[mi][1] = *(const i64*)(arow + mi * 1024 + 32);   // k-half 1
    }
#pragma unroll
    for (int ni = 0; ni < 4; ni++) {
      bf[ni][0] = *(const i64*)(brow + ni * 1024);
      bf[ni][1] = *(const i64*)(brow + ni * 1024 + 32);
    }
#pragma unroll
    for (int half = 0; half < 2; half++)
#pragma unroll
      for (int mi = 0; mi < 4; mi++)
#pragma unroll
        for (int ni = 0; ni < 4; ni++)
          acc[mi][ni] = __builtin_amdgcn_mfma_f32_16x16x32_fp8_fp8(
              af[mi][half], bf[ni][half], acc[mi][ni], 0, 0, 0);
  }

  // epilogue: v = m_sq[j] - 2*dot ; min over this block's 128-col slab
  float msql[4];
#pragma unroll
  for (int ni = 0; ni < 4; ni++)
    msql[ni] = msq[col0 + wn * 64 + ni * 16 + l16];

#pragma unroll
  for (int mi = 0; mi < 4; mi++) {
#pragma unroll
    for (int r = 0; r < 4; r++) {
      float v = msql[0] - 2.f * acc[mi][0][r];
#pragma unroll
      for (int ni = 1; ni < 4; ni++)
        v = fminf(v, msql[ni] - 2.f * acc[mi][ni][r]);
      v = fminf(v, __shfl_xor(v, 1, 64));
      v = fminf(v, __shfl_xor(v, 2, 64));
      v = fminf(v, __shfl_xor(v, 4, 64));
      v = fminf(v, __shfl_xor(v, 8, 64));
      if (l16 == 0) {
        int lrow = wm * 64 + mi * 16 + quad * 4 + r;  // C/D: row = quad*4 + reg
        atomicMin(&smin[lrow], fkey(v));
      }
    }
  }
  __syncthreads();
  if (t < 128) atomicMin(&dmin[row0 + t], smin[t]);
}

// ------- Kernel D: sqrt + 28->224 bilinear + per-image max (16x8 blocks) ----
__global__ void finalize(const unsigned* __restrict__ dmin,
                         const float* __restrict__ xsq,
                         float* __restrict__ out) {
  const int b = blockIdx.x, slice = blockIdx.y, t = threadIdx.x;
  __shared__ float smap[784];
  __shared__ float sred[4];
  for (int i = t; i < 784; i += 256) {
    float d2 = xsq[b * 784 + i] + funkey(dmin[b * 784 + i]);
    smap[i] = sqrtf(fmaxf(d2, 0.f));
  }
  __syncthreads();
  float* omap = out + (size_t)b * 50176;
  float tmax = 0.f;
  const int p0 = slice * 6272;           // 28 output rows per slice
  for (int p = p0 + t; p < p0 + 6272; p += 256) {
    const int Y = p / 224, Xp = p % 224;
    const float sy = Y * 0.125f - 0.4375f;   // (dst+0.5)/8 - 0.5
    const float sx = Xp * 0.125f - 0.4375f;
    const int y0 = (int)floorf(sy); const float fy = sy - (float)y0;
    const int x0 = (int)floorf(sx); const float fx = sx - (float)x0;
    const int y0c = max(y0, 0), y1c = min(y0 + 1, 27);
    const int x0c = max(x0, 0), x1c = min(x0 + 1, 27);
    float v = (1.f-fy)*((1.f-fx)*smap[y0c*28+x0c] + fx*smap[y0c*28+x1c])
            +      fy *((1.f-fx)*smap[y1c*28+x0c] + fx*smap[y1c*28+x1c]);
    omap[p] = v;
    tmax = fmaxf(tmax, v);
  }
  for (int off = 32; off > 0; off >>= 1)
    tmax = fmaxf(tmax, __shfl_down(tmax, off, 64));
  if ((t & 63) == 0) sred[t >> 6] = tmax;
  __syncthreads();
  if (t == 0) {
    float m = fmaxf(fmaxf(sred[0], sred[1]), fmaxf(sred[2], sred[3]));
    // values >= 0: uint bit-pattern order == float order
    atomicMax((unsigned*)(out + 802816 + b), __float_as_uint(m));
  }
}

extern "C" void kernel_launch(void* const* d_in, const int* in_sizes, int n_in,
                              void* d_out, int out_size, void* d_ws, size_t ws_size,
                              hipStream_t stream) {
  const float* feat2 = (const float*)d_in[0];  // [16,512,28,28]
  const float* feat3 = (const float*)d_in[1];  // [16,1024,14,14]
  const float* mb    = (const float*)d_in[2];  // [16384,1536]
  char* ws = (char*)d_ws;
  u8*       feats = (u8*)ws;                           // 12544*1536 = 19,267,584
  u8*       mbb   = (u8*)(ws + 19267584);              // 16384*1536 = 25,165,824
  float*    xsq   = (float*)(ws + 44433408);           // 12544*4
  float*    msq   = (float*)(ws + 44483584);           // 16384*4
  unsigned* dmin  = (unsigned*)(ws + 44549120);        // 12544*4
  float* out = (float*)d_out;

  prep_feats<<<N_ROWS, 256, 0, stream>>>(feat2, feat3, feats, xsq);
  prep_mb<<<M_ROWS, 384, 0, stream>>>(mb, mbb, msq);
  init_min<<<(N_ROWS + 255) / 256, 256, 0, stream>>>(
      dmin, (unsigned*)(out + 802816));
  gemm_min<<<dim3(128, 98), 256, 0, stream>>>(feats, mbb, msq, dmin);
  finalize<<<dim3(BATCH, 8), 256, 0, stream>>>(dmin, xsq, out);
}

// Round 6
// 716.966 us; speedup vs baseline: 1.9704x; 1.9704x over previous
//
#include <hip/hip_runtime.h>
#include <math.h>

#define N_ROWS 12544   // 16*28*28
#define C_DIM  1536
#define M_ROWS 16384
#define BATCH  16

typedef long  i64;
typedef float f32x4 __attribute__((ext_vector_type(4)));
typedef unsigned char u8;

// order-preserving float->uint key for atomicMin
__device__ __forceinline__ unsigned fkey(float f) {
  unsigned u = __float_as_uint(f);
  return (u & 0x80000000u) ? ~u : (u | 0x80000000u);
}
__device__ __forceinline__ float funkey(unsigned k) {
  unsigned u = (k & 0x80000000u) ? (k ^ 0x80000000u) : ~k;
  return __uint_as_float(u);
}

__device__ __forceinline__ void gl_lds16(const void* g, void* l) {
  __builtin_amdgcn_global_load_lds(
      (__attribute__((address_space(1))) void*)(g),
      (__attribute__((address_space(3))) void*)(l), 16, 0, 0);
}

// ---------------- Kernel A: build fp8 e4m3 feature rows + x_sq -------------
__global__ void prep_feats(const float* __restrict__ feat2,
                           const float* __restrict__ feat3,
                           u8* __restrict__ feats,
                           float* __restrict__ xsq) {
  const int n = blockIdx.x;
  const int t = threadIdx.x;
  const int b = n / 784;
  const int rem = n % 784;
  const int y = rem / 28, x = rem % 28;
  const float sy = 0.5f * y - 0.25f;
  const float sx = 0.5f * x - 0.25f;
  const int y0 = (int)floorf(sy); const float fy = sy - (float)y0;
  const int x0 = (int)floorf(sx); const float fx = sx - (float)x0;
  const int y0c = max(y0, 0), y1c = min(y0 + 1, 13);
  const int x0c = max(x0, 0), x1c = min(x0 + 1, 13);
  const float w00 = (1.f-fy)*(1.f-fx), w01 = (1.f-fy)*fx;
  const float w10 = fy*(1.f-fx),       w11 = fy*fx;

  float ssq = 0.f;
  u8* orow = feats + (size_t)n * C_DIM;
  for (int c = t; c < C_DIM; c += 256) {
    float v;
    if (c < 512) {
      v = feat2[(((size_t)b * 512 + c) * 28 + y) * 28 + x];
    } else {
      const float* f3 = feat3 + ((size_t)b * 1024 + (c - 512)) * 196;
      v = w00 * f3[y0c*14 + x0c] + w01 * f3[y0c*14 + x1c]
        + w10 * f3[y1c*14 + x0c] + w11 * f3[y1c*14 + x1c];
    }
    int p = __builtin_amdgcn_cvt_pk_fp8_f32(v, 0.f, 0, false);  // e4m3 on gfx950
    orow[c] = (u8)(p & 0xFF);
    float vb = __builtin_amdgcn_cvt_f32_fp8(p, 0);
    ssq += vb * vb;
  }
  __shared__ float sred[4];
  for (int off = 32; off > 0; off >>= 1) ssq += __shfl_down(ssq, off, 64);
  if ((t & 63) == 0) sred[t >> 6] = ssq;
  __syncthreads();
  if (t == 0) xsq[n] = sred[0] + sred[1] + sred[2] + sred[3];
}

// ---------------- Kernel B: fp8 memory bank + m_sq ----------------
__global__ __launch_bounds__(384) void prep_mb(
    const float* __restrict__ mb, u8* __restrict__ mbb,
    float* __restrict__ msq) {
  const int j = blockIdx.x, t = threadIdx.x;   // 384 threads * 4 floats = 1536
  const float4 v = *(const float4*)(mb + (size_t)j * C_DIM + t * 4);
  int w = __builtin_amdgcn_cvt_pk_fp8_f32(v.x, v.y, 0, false);
  w = __builtin_amdgcn_cvt_pk_fp8_f32(v.z, v.w, w, true);      // bytes 2,3
  *(unsigned*)(mbb + (size_t)j * C_DIM + t * 4) = (unsigned)w;
  float q0 = __builtin_amdgcn_cvt_f32_fp8(w, 0);
  float q1 = __builtin_amdgcn_cvt_f32_fp8(w, 1);
  float q2 = __builtin_amdgcn_cvt_f32_fp8(w, 2);
  float q3 = __builtin_amdgcn_cvt_f32_fp8(w, 3);
  float ssq = q0*q0 + q1*q1 + q2*q2 + q3*q3;
  __shared__ float sred[6];
  for (int off = 32; off > 0; off >>= 1) ssq += __shfl_down(ssq, off, 64);
  if ((t & 63) == 0) sred[t >> 6] = ssq;
  __syncthreads();
  if (t == 0) {
    float s = 0.f;
#pragma unroll
    for (int w2 = 0; w2 < 6; w2++) s += sred[w2];
    msq[j] = s;
  }
}

// ---------------- init min buffer + score slots ----------------
__global__ void init_min(unsigned* __restrict__ dmin,
                         unsigned* __restrict__ score) {
  int i = blockIdx.x * 256 + threadIdx.x;
  if (i < N_ROWS) dmin[i] = 0xFFFFFFFFu;
  if (i < BATCH) score[i] = 0u;   // 0.0f; anomaly values are >= 0
}

// ---------------- Kernel C: fp8 MFMA GEMM + fused min over M ----------------
// 128x128 tile, BK=64 fp8 bytes, XOR-swizzled LDS (R2-verified pattern):
// row r (64B = 4 slots of 16B); slot s holds global 16B chunk c = s ^ ((r>>1)&3).
//  - staging: identical addressing to R2 (rows are 64B there too) -> coalesced,
//    conflict-free
//  - fragment ds_read_b64 at offset ((c ^ ((l16>>1)&3))*16) + (quad&1)*8:
//    every bank hit <=2-way (free, m136); half1 offset = half0 ^ 32
__global__ void gemm_min(const u8* __restrict__ X, const u8* __restrict__ Mb,
                         const float* __restrict__ msq,
                         unsigned* __restrict__ dmin) {
  __shared__ u8 As[128 * 64];
  __shared__ u8 Bs[128 * 64];
  __shared__ unsigned smin[128];
  const int t = threadIdx.x;
  const int mtile = blockIdx.x;   // 0..127 over M
  const int ntile = blockIdx.y;   // 0..97  over N
  const int lane = t & 63, wave = t >> 6;
  const int wm = wave >> 1, wn = wave & 1;
  if (t < 128) smin[t] = 0xFFFFFFFFu;

  const int row0 = ntile * 128;
  const int col0 = mtile * 128;
  // staging: thread t fills LDS slot (row=t>>2, slot=t&3); global chunk
  // c = (t&3) ^ ((t>>3)&3)
  const int s_row = t >> 2;
  const int s_ch  = (t & 3) ^ ((t >> 3) & 3);
  const u8* ga = X  + (size_t)(row0 + s_row) * C_DIM + s_ch * 16;
  const u8* gb = Mb + (size_t)(col0 + s_row) * C_DIM + s_ch * 16;
  u8* la = As + t * 16;
  u8* lb = Bs + t * 16;

  f32x4 acc[4][4];
  const f32x4 zero = {0.f, 0.f, 0.f, 0.f};
#pragma unroll
  for (int mi = 0; mi < 4; mi++)
#pragma unroll
    for (int ni = 0; ni < 4; ni++) acc[mi][ni] = zero;

  const int quad = lane >> 4, l16 = lane & 15;
  // fragment: wants chunk c = half*2 + (quad>>1), byte (quad&1)*8 within it.
  // LDS slot = c ^ fsw, fsw = (l16>>1)&3 (row base is a multiple of 16).
  const int fsw = (l16 >> 1) & 3;
  const int hoff0 = (((quad >> 1) ^ fsw) * 16) + (quad & 1) * 8;
  const int hoff1 = hoff0 ^ 32;   // chunk c XOR 2 -> slot byte offset XOR 32
  const u8* arow = As + (wm * 64 + l16) * 64;
  const u8* brow = Bs + (wn * 64 + l16) * 64;

  for (int k0 = 0; k0 < C_DIM; k0 += 64) {
    __syncthreads();
    gl_lds16(ga + k0,               la);
    gl_lds16(ga + 64 * C_DIM + k0,  la + 4096);   // rows 64..127
    gl_lds16(gb + k0,               lb);
    gl_lds16(gb + 64 * C_DIM + k0,  lb + 4096);
    __syncthreads();
    i64 af[4][2], bf[4][2];
#pragma unroll
    for (int mi = 0; mi < 4; mi++) {
      af[mi][0] = *(const i64*)(arow + mi * 1024 + hoff0);  // +16 rows = 1024B
      af[mi][1] = *(const i64*)(arow + mi * 1024 + hoff1);
    }
#pragma unroll
    for (int ni = 0; ni < 4; ni++) {
      bf[ni][0] = *(const i64*)(brow + ni * 1024 + hoff0);
      bf[ni][1] = *(const i64*)(brow + ni * 1024 + hoff1);
    }
#pragma unroll
    for (int half = 0; half < 2; half++)
#pragma unroll
      for (int mi = 0; mi < 4; mi++)
#pragma unroll
        for (int ni = 0; ni < 4; ni++)
          acc[mi][ni] = __builtin_amdgcn_mfma_f32_16x16x32_fp8_fp8(
              af[mi][half], bf[ni][half], acc[mi][ni], 0, 0, 0);
  }

  // epilogue: v = m_sq[j] - 2*dot ; min over this block's 128-col slab
  float msql[4];
#pragma unroll
  for (int ni = 0; ni < 4; ni++)
    msql[ni] = msq[col0 + wn * 64 + ni * 16 + l16];

#pragma unroll
  for (int mi = 0; mi < 4; mi++) {
#pragma unroll
    for (int r = 0; r < 4; r++) {
      float v = msql[0] - 2.f * acc[mi][0][r];
#pragma unroll
      for (int ni = 1; ni < 4; ni++)
        v = fminf(v, msql[ni] - 2.f * acc[mi][ni][r]);
      v = fminf(v, __shfl_xor(v, 1, 64));
      v = fminf(v, __shfl_xor(v, 2, 64));
      v = fminf(v, __shfl_xor(v, 4, 64));
      v = fminf(v, __shfl_xor(v, 8, 64));
      if (l16 == 0) {
        int lrow = wm * 64 + mi * 16 + quad * 4 + r;  // C/D: row = quad*4 + reg
        atomicMin(&smin[lrow], fkey(v));
      }
    }
  }
  __syncthreads();
  if (t < 128) atomicMin(&dmin[row0 + t], smin[t]);
}

// ------- Kernel D: sqrt + 28->224 bilinear + per-image max (16x8 blocks) ----
__global__ void finalize(const unsigned* __restrict__ dmin,
                         const float* __restrict__ xsq,
                         float* __restrict__ out) {
  const int b = blockIdx.x, slice = blockIdx.y, t = threadIdx.x;
  __shared__ float smap[784];
  __shared__ float sred[4];
  for (int i = t; i < 784; i += 256) {
    float d2 = xsq[b * 784 + i] + funkey(dmin[b * 784 + i]);
    smap[i] = sqrtf(fmaxf(d2, 0.f));
  }
  __syncthreads();
  float* omap = out + (size_t)b * 50176;
  float tmax = 0.f;
  const int p0 = slice * 6272;           // 28 output rows per slice
  for (int p = p0 + t; p < p0 + 6272; p += 256) {
    const int Y = p / 224, Xp = p % 224;
    const float sy = Y * 0.125f - 0.4375f;   // (dst+0.5)/8 - 0.5
    const float sx = Xp * 0.125f - 0.4375f;
    const int y0 = (int)floorf(sy); const float fy = sy - (float)y0;
    const int x0 = (int)floorf(sx); const float fx = sx - (float)x0;
    const int y0c = max(y0, 0), y1c = min(y0 + 1, 27);
    const int x0c = max(x0, 0), x1c = min(x0 + 1, 27);
    float v = (1.f-fy)*((1.f-fx)*smap[y0c*28+x0c] + fx*smap[y0c*28+x1c])
            +      fy *((1.f-fx)*smap[y1c*28+x0c] + fx*smap[y1c*28+x1c]);
    omap[p] = v;
    tmax = fmaxf(tmax, v);
  }
  for (int off = 32; off > 0; off >>= 1)
    tmax = fmaxf(tmax, __shfl_down(tmax, off, 64));
  if ((t & 63) == 0) sred[t >> 6] = tmax;
  __syncthreads();
  if (t == 0) {
    float m = fmaxf(fmaxf(sred[0], sred[1]), fmaxf(sred[2], sred[3]));
    // values >= 0: uint bit-pattern order == float order
    atomicMax((unsigned*)(out + 802816 + b), __float_as_uint(m));
  }
}

extern "C" void kernel_launch(void* const* d_in, const int* in_sizes, int n_in,
                              void* d_out, int out_size, void* d_ws, size_t ws_size,
                              hipStream_t stream) {
  const float* feat2 = (const float*)d_in[0];  // [16,512,28,28]
  const float* feat3 = (const float*)d_in[1];  // [16,1024,14,14]
  const float* mb    = (const float*)d_in[2];  // [16384,1536]
  char* ws = (char*)d_ws;
  u8*       feats = (u8*)ws;                           // 12544*1536 = 19,267,584
  u8*       mbb   = (u8*)(ws + 19267584);              // 16384*1536 = 25,165,824
  float*    xsq   = (float*)(ws + 44433408);           // 12544*4
  float*    msq   = (float*)(ws + 44483584);           // 16384*4
  unsigned* dmin  = (unsigned*)(ws + 44549120);        // 12544*4
  float* out = (float*)d_out;

  prep_feats<<<N_ROWS, 256, 0, stream>>>(feat2, feat3, feats, xsq);
  prep_mb<<<M_ROWS, 384, 0, stream>>>(mb, mbb, msq);
  init_min<<<(N_ROWS + 255) / 256, 256, 0, stream>>>(
      dmin, (unsigned*)(out + 802816));
  gemm_min<<<dim3(128, 98), 256, 0, stream>>>(feats, mbb, msq, dmin);
  finalize<<<dim3(BATCH, 8), 256, 0, stream>>>(dmin, xsq, out);
}